// Round 3
// baseline (814.955 us; speedup 1.0000x reference)
//
#include <hip/hip_runtime.h>

// ---------------- constants ----------------
#define NTOK 65536
#define DIN  1024
#define H    512
#define HH   256
#define NREG 16
#define MPR  4096   // patches per region = NTOK/NREG

// ---------------- helpers ----------------
__device__ __forceinline__ unsigned short f2bf(float f) {
  unsigned u = __float_as_uint(f);
  u += 0x7fffu + ((u >> 16) & 1u);   // RNE
  return (unsigned short)(u >> 16);
}
__device__ __forceinline__ float bf2f(unsigned short s) {
  return __uint_as_float(((unsigned)s) << 16);
}
// A&S 7.1.26 erf, |err| < 1.5e-7 (far below Eb's bf16 quantum)
__device__ __forceinline__ float gelu_fast(float x) {
  float ax = fabsf(x) * 0.70710678118654752f;   // |x|/sqrt(2)
  float t  = 1.0f / fmaf(0.3275911f, ax, 1.0f);
  float poly = t * fmaf(t, fmaf(t, fmaf(t, fmaf(t, 1.061405429f, -1.453152027f),
                                        1.421413741f), -0.284496736f), 0.254829592f);
  float erfv = fmaf(-poly, __expf(-ax * ax), 1.0f);
  float s = (x >= 0.0f) ? erfv : -erfv;
  return 0.5f * x * (1.0f + s);
}
__device__ __forceinline__ float tanh_fast(float x) {
  float e = __expf(2.0f * x);        // x<<0 -> 0 -> -1 ; x>>0 -> inf -> +1
  return 1.0f - 2.0f / (e + 1.0f);
}

typedef __attribute__((ext_vector_type(8))) short shortx8;  // 8 bf16 (4 VGPRs)
typedef __attribute__((ext_vector_type(4))) float floatx4;  // 4 fp32

__device__ __forceinline__ void gl_lds16(const void* g, void* l) {
  __builtin_amdgcn_global_load_lds(
      (const __attribute__((address_space(1))) void*)g,
      (__attribute__((address_space(3))) void*)l, 16, 0, 0);
}

// ---------------- KC: X fp32 -> bf16 (streaming convert) ----------------
__global__ __launch_bounds__(256) void kc_convert(const float* __restrict__ X,
                                                  unsigned short* __restrict__ Xb) {
  size_t i = ((size_t)blockIdx.x * 256 + threadIdx.x) * 8;
  const floatx4* src = (const floatx4*)(X + i);
  floatx4 f0 = src[0], f1 = src[1];
  shortx8 h;
  h[0] = (short)f2bf(f0[0]); h[1] = (short)f2bf(f0[1]);
  h[2] = (short)f2bf(f0[2]); h[3] = (short)f2bf(f0[3]);
  h[4] = (short)f2bf(f1[0]); h[5] = (short)f2bf(f1[1]);
  h[6] = (short)f2bf(f1[2]); h[7] = (short)f2bf(f1[3]);
  *(shortx8*)(Xb + i) = h;
}

// ---------------- K0: weight transpose + bf16 convert ----------------
__global__ __launch_bounds__(256) void k0_prep(const float* __restrict__ W1,
                                               const float* __restrict__ Wa1,
                                               unsigned short* __restrict__ W1t,
                                               unsigned short* __restrict__ Wa1t) {
  int idx = blockIdx.x * 256 + threadIdx.x;
  if (idx < DIN * H) {                 // 524288
    int n = idx >> 10, k = idx & 1023; // W1t[n][k] = W1[k][n]
    W1t[idx] = f2bf(W1[k * H + n]);
  } else {
    int i2 = idx - DIN * H;            // < 131072
    int n = i2 >> 9, k = i2 & 511;     // Wa1t[n][k] = Wa1[k][n]
    Wa1t[i2] = f2bf(Wa1[k * HH + n]);
  }
}

// LDS tiles: 128 rows x 64 shorts (8 x 16B chunks/row, 128 B = full bank wrap).
// XOR swizzle: physical chunk = logical chunk ^ (row & 7). Fragment reads then
// alias only 2-way (free, m136). Staging inverse-permutes the GLOBAL chunk
// index (permutation stays within the row's 128 B -> coalescing preserved).

// ---------------- K12: fused  Eb = GELU(Xb@W1t^T + b1)  then
//                  scores = tanh(Eb@Wa1t^T + ba1) . Wa2  (per 128-row block) --
// grid(512), 256 thr. Phase 1: 4 column-tiles of 128 (BN=512 total), BK=64.
// Phase 2: this block's own Eb rows (L2-hot) @ Wa1t, full K=512 -> direct store.
__global__ __launch_bounds__(256) void k12_fused(const unsigned short* __restrict__ Xb,
                                                 const unsigned short* __restrict__ W1t,
                                                 const float* __restrict__ b1,
                                                 const unsigned short* __restrict__ Wa1t,
                                                 const float* __restrict__ ba1,
                                                 const float* __restrict__ Wa2,
                                                 unsigned short* __restrict__ Eb,
                                                 float* __restrict__ scores) {
  __shared__ __align__(16) short lA[128 * 64];   // 16 KB
  __shared__ __align__(16) short lB[128 * 64];   // 16 KB
  __shared__ float scomb[256];
  const int tid = threadIdx.x;
  const int rowBase = blockIdx.x * 128;
  const int lane = tid & 63;
  const int wave = tid >> 6;
  const int wr = wave >> 1, wc = wave & 1;       // 2x2 waves of 64x64
  const int l15 = lane & 15, quad = lane >> 4;
  const int rsw = l15 & 7;                       // fragment-read swizzle term

  // ---------------- phase 1: region encoder ----------------
  for (int ct = 0; ct < 4; ct++) {
    floatx4 acc[4][4] = {};
    for (int kb = 0; kb < DIN; kb += 64) {
      __syncthreads();
#pragma unroll
      for (int s = 0; s < 4; s++) {
        int c = tid + s * 256;
        int row = c >> 3;
        int kc_ = (c & 7) ^ (row & 7);           // inverse of XOR swizzle
        gl_lds16(Xb + (size_t)(rowBase + row) * DIN + kb + kc_ * 8, &lA[c * 8]);
        gl_lds16(W1t + (size_t)(ct * 128 + row) * DIN + kb + kc_ * 8, &lB[c * 8]);
      }
      __syncthreads();
#pragma unroll
      for (int h = 0; h < 2; h++) {
        shortx8 aF[4], bF[4];
#pragma unroll
        for (int i = 0; i < 4; i++)
          aF[i] = *(const shortx8*)(&lA[(wr * 64 + i * 16 + l15) * 64 + (((h << 2) + quad) ^ rsw) * 8]);
#pragma unroll
        for (int j = 0; j < 4; j++)
          bF[j] = *(const shortx8*)(&lB[(wc * 64 + j * 16 + l15) * 64 + (((h << 2) + quad) ^ rsw) * 8]);
#pragma unroll
        for (int i = 0; i < 4; i++)
#pragma unroll
          for (int j = 0; j < 4; j++)
            acc[i][j] = __builtin_amdgcn_mfma_f32_16x16x32_bf16(aF[i], bF[j], acc[i][j], 0, 0, 0);
      }
    }
    // epilogue: bias + fast-exact GELU + bf16 store
    const int row0 = rowBase + wr * 64;
    const int col0 = ct * 128 + wc * 64;
#pragma unroll
    for (int j = 0; j < 4; j++) {
      int col = col0 + j * 16 + l15;
      float bias = b1[col];
#pragma unroll
      for (int i = 0; i < 4; i++) {
        int rb = row0 + i * 16 + quad * 4;
#pragma unroll
        for (int v = 0; v < 4; v++)
          Eb[(size_t)(rb + v) * H + col] = f2bf(gelu_fast(acc[i][j][v] + bias));
      }
    }
  }

  // make this block's Eb stores visible to its own gl_lds reads (L1 invalidate)
  __threadfence();

  // ---------------- phase 2: attention scores (full K in-block) ----------------
  float p[4][4];
#pragma unroll
  for (int i = 0; i < 4; i++)
#pragma unroll
    for (int v = 0; v < 4; v++) p[i][v] = 0.0f;

  for (int n2 = 0; n2 < 2; n2++) {
    floatx4 acc[4][4] = {};
    for (int kb = 0; kb < H; kb += 64) {
      __syncthreads();
#pragma unroll
      for (int s = 0; s < 4; s++) {
        int c = tid + s * 256;
        int row = c >> 3;
        int kc_ = (c & 7) ^ (row & 7);
        gl_lds16(Eb + (size_t)(rowBase + row) * H + kb + kc_ * 8, &lA[c * 8]);
        gl_lds16(Wa1t + (size_t)(n2 * 128 + row) * H + kb + kc_ * 8, &lB[c * 8]);
      }
      __syncthreads();
#pragma unroll
      for (int h = 0; h < 2; h++) {
        shortx8 aF[4], bF[4];
#pragma unroll
        for (int i = 0; i < 4; i++)
          aF[i] = *(const shortx8*)(&lA[(wr * 64 + i * 16 + l15) * 64 + (((h << 2) + quad) ^ rsw) * 8]);
#pragma unroll
        for (int j = 0; j < 4; j++)
          bF[j] = *(const shortx8*)(&lB[(wc * 64 + j * 16 + l15) * 64 + (((h << 2) + quad) ^ rsw) * 8]);
#pragma unroll
        for (int i = 0; i < 4; i++)
#pragma unroll
          for (int j = 0; j < 4; j++)
            acc[i][j] = __builtin_amdgcn_mfma_f32_16x16x32_bf16(aF[i], bF[j], acc[i][j], 0, 0, 0);
      }
    }
    // partial epilogue: tanh + dot with Wa2 (accumulate across n2 passes)
#pragma unroll
    for (int j = 0; j < 4; j++) {
      int col = n2 * 128 + wc * 64 + j * 16 + l15;
      float bias = ba1[col];
      float wa2 = Wa2[col];
#pragma unroll
      for (int i = 0; i < 4; i++)
#pragma unroll
        for (int v = 0; v < 4; v++)
          p[i][v] += tanh_fast(acc[i][j][v] + bias) * wa2;
    }
  }
  // reduce over the 16 column-lanes
#pragma unroll
  for (int i = 0; i < 4; i++)
#pragma unroll
    for (int v = 0; v < 4; v++) {
      float t = p[i][v];
      t += __shfl_xor(t, 1, 16);
      t += __shfl_xor(t, 2, 16);
      t += __shfl_xor(t, 4, 16);
      t += __shfl_xor(t, 8, 16);
      p[i][v] = t;
    }
  __syncthreads();
  if (l15 == 0) {
#pragma unroll
    for (int i = 0; i < 4; i++)
#pragma unroll
      for (int v = 0; v < 4; v++)
        scomb[(wr * 64 + i * 16 + quad * 4 + v) * 2 + wc] = p[i][v];
  }
  __syncthreads();
  if (tid < 128) scores[rowBase + tid] = scomb[tid * 2] + scomb[tid * 2 + 1];
}

// ---------------- K3a: per-region softmax weights ----------------
__global__ __launch_bounds__(256) void k3a_softmax(const float* __restrict__ scores,
                                                   float* __restrict__ wts) {
  const int r = blockIdx.x, tid = threadIdx.x;
  __shared__ float red[256];
  float m = -1e30f;
  for (int j = tid; j < MPR; j += 256) m = fmaxf(m, scores[r + NREG * j]);
  red[tid] = m;
  __syncthreads();
  for (int s = 128; s > 0; s >>= 1) {
    if (tid < s) red[tid] = fmaxf(red[tid], red[tid + s]);
    __syncthreads();
  }
  float mx = red[0];
  __syncthreads();
  float sum = 0.0f;
  for (int j = tid; j < MPR; j += 256) sum += expf(scores[r + NREG * j] - mx);
  red[tid] = sum;
  __syncthreads();
  for (int s = 128; s > 0; s >>= 1) {
    if (tid < s) red[tid] += red[tid + s];
    __syncthreads();
  }
  float inv = 1.0f / red[0];
  for (int j = tid; j < MPR; j += 256)
    wts[r + NREG * j] = expf(scores[r + NREG * j] - mx) * inv;
}

// ---------------- K3b: region_features[r][h] = sum_m w * Eb ----------------
__global__ __launch_bounds__(256) void k3b_wsum(const unsigned short* __restrict__ Eb,
                                                const float* __restrict__ wts,
                                                float* __restrict__ rf) {
  const int r = blockIdx.y;
  const int mc = blockIdx.x;
  const int tid = threadIdx.x;
  float a0 = 0.0f, a1 = 0.0f;
  for (int j = mc * 128; j < mc * 128 + 128; j++) {
    int n = r + NREG * j;
    float w = wts[n];
    unsigned v = *(const unsigned*)(Eb + (size_t)n * H + tid * 2);
    a0 += w * bf2f((unsigned short)(v & 0xffffu));
    a1 += w * bf2f((unsigned short)(v >> 16));
  }
  atomicAdd(&rf[r * H + tid * 2], a0);
  atomicAdd(&rf[r * H + tid * 2 + 1], a1);
}

// ---------------- K4ab: slide_emb + slide attention score (fused) ----------------
__global__ __launch_bounds__(256) void k4ab_slide(const float* __restrict__ rf,
                                                  const float* __restrict__ Ws,
                                                  const float* __restrict__ bs,
                                                  const float* __restrict__ Wsa1,
                                                  const float* __restrict__ bsa1,
                                                  const float* __restrict__ Wsa2,
                                                  const float* __restrict__ bsa2,
                                                  float* __restrict__ se,
                                                  float* __restrict__ ss) {
  const int r = blockIdx.x, tid = threadIdx.x;
  __shared__ float lrf[H];
  __shared__ float lse[H];
  __shared__ float red[256];
  lrf[tid] = rf[r * H + tid];
  lrf[tid + 256] = rf[r * H + tid + 256];
  __syncthreads();
  float a0 = 0.0f, a1 = 0.0f;
  for (int k = 0; k < H; k++) {
    float x = lrf[k];
    a0 += x * Ws[k * H + tid];
    a1 += x * Ws[k * H + tid + 256];
  }
  float s0 = gelu_fast(a0 + bs[tid]);
  float s1 = gelu_fast(a1 + bs[tid + 256]);
  se[r * H + tid] = s0;
  se[r * H + tid + 256] = s1;
  lse[tid] = s0;
  lse[tid + 256] = s1;
  __syncthreads();
  float a = 0.0f;
  for (int k = 0; k < H; k++) a += lse[k] * Wsa1[k * HH + tid];
  red[tid] = tanh_fast(a + bsa1[tid]) * Wsa2[tid];
  __syncthreads();
  for (int s = 128; s > 0; s >>= 1) {
    if (tid < s) red[tid] += red[tid + s];
    __syncthreads();
  }
  if (tid == 0) ss[r] = red[0] + bsa2[0];
}

// ---------------- K4c: softmax over regions + classifier ----------------
__global__ __launch_bounds__(256) void k4c_final(const float* __restrict__ se,
                                                 const float* __restrict__ ss,
                                                 const float* __restrict__ Wc1,
                                                 const float* __restrict__ bc1,
                                                 const float* __restrict__ Wc2,
                                                 const float* __restrict__ bc2,
                                                 float* __restrict__ out) {
  const int tid = threadIdx.x;
  __shared__ float srep[H];
  __shared__ float r0[256], r1[256];
  float mx = -1e30f;
  for (int i = 0; i < NREG; i++) mx = fmaxf(mx, ss[i]);
  float wv[NREG];
  float den = 0.0f;
  for (int i = 0; i < NREG; i++) { wv[i] = expf(ss[i] - mx); den += wv[i]; }
  float inv = 1.0f / den;
  float s0 = 0.0f, s1 = 0.0f;
  for (int i = 0; i < NREG; i++) {
    float w = wv[i] * inv;
    s0 += w * se[i * H + tid];
    s1 += w * se[i * H + tid + 256];
  }
  srep[tid] = s0;
  srep[tid + 256] = s1;
  __syncthreads();
  float a = 0.0f;
  for (int k = 0; k < H; k++) a += srep[k] * Wc1[k * HH + tid];
  float g = gelu_fast(a + bc1[tid]);
  r0[tid] = g * Wc2[tid * 2];
  r1[tid] = g * Wc2[tid * 2 + 1];
  __syncthreads();
  for (int s = 128; s > 0; s >>= 1) {
    if (tid < s) { r0[tid] += r0[tid + s]; r1[tid] += r1[tid + s]; }
    __syncthreads();
  }
  if (tid == 0) {
    out[0] = r0[0] + bc2[0];
    out[1] = r1[0] + bc2[1];
  }
}

// ---------------- launcher ----------------
extern "C" void kernel_launch(void* const* d_in, const int* in_sizes, int n_in,
                              void* d_out, int out_size, void* d_ws, size_t ws_size,
                              hipStream_t stream) {
  const float* X    = (const float*)d_in[0];
  const float* W1   = (const float*)d_in[1];
  const float* b1   = (const float*)d_in[2];
  const float* Wa1  = (const float*)d_in[3];
  const float* ba1  = (const float*)d_in[4];
  const float* Wa2  = (const float*)d_in[5];
  // d_in[6] = ba2: constant shift inside softmax -> no effect, unused
  const float* Ws   = (const float*)d_in[7];
  const float* bs   = (const float*)d_in[8];
  const float* Wsa1 = (const float*)d_in[9];
  const float* bsa1 = (const float*)d_in[10];
  const float* Wsa2 = (const float*)d_in[11];
  const float* bsa2 = (const float*)d_in[12];
  const float* Wc1  = (const float*)d_in[13];
  const float* bc1  = (const float*)d_in[14];
  const float* Wc2  = (const float*)d_in[15];
  const float* bc2  = (const float*)d_in[16];
  float* out = (float*)d_out;

  char* ws = (char*)d_ws;
  constexpr size_t OFF_W1T  = 0;                                    // 1 MiB
  constexpr size_t OFF_WA1T = OFF_W1T + (size_t)H * DIN * 2;        // +256 KiB
  constexpr size_t OFF_EB   = OFF_WA1T + (size_t)HH * H * 2;        // +64 MiB
  constexpr size_t OFF_SC   = OFF_EB + (size_t)NTOK * H * 2;        // scores 256 KiB
  constexpr size_t OFF_RF   = OFF_SC + (size_t)NTOK * 4;            // rf 32 KiB
  constexpr size_t OFF_WT   = OFF_RF + (size_t)NREG * H * 4;        // wts 256 KiB
  constexpr size_t OFF_SE   = OFF_WT + (size_t)NTOK * 4;            // se 32 KiB
  constexpr size_t OFF_SS   = OFF_SE + (size_t)NREG * H * 4;        // ss 64 B
  constexpr size_t OFF_XB   = OFF_SS + 256;                         // Xb 128 MiB

  unsigned short* W1t  = (unsigned short*)(ws + OFF_W1T);
  unsigned short* Wa1t = (unsigned short*)(ws + OFF_WA1T);
  unsigned short* Eb   = (unsigned short*)(ws + OFF_EB);
  float* scores = (float*)(ws + OFF_SC);
  float* rf     = (float*)(ws + OFF_RF);
  float* wts    = (float*)(ws + OFF_WT);
  float* se     = (float*)(ws + OFF_SE);
  float* ssb    = (float*)(ws + OFF_SS);
  unsigned short* Xb = (unsigned short*)(ws + OFF_XB);

  // zero only the rf atomic accumulator (scores now direct-stored by k12)
  hipMemsetAsync(rf, 0, (size_t)NREG * H * 4, stream);

  kc_convert<<<(NTOK * (size_t)DIN / 8 + 255) / 256, 256, 0, stream>>>(X, Xb);
  k0_prep<<<(DIN * H + HH * H) / 256, 256, 0, stream>>>(W1, Wa1, W1t, Wa1t);
  k12_fused<<<512, 256, 0, stream>>>(Xb, W1t, b1, Wa1t, ba1, Wa2, Eb, scores);
  k3a_softmax<<<NREG, 256, 0, stream>>>(scores, wts);
  k3b_wsum<<<dim3(32, NREG), 256, 0, stream>>>(Eb, wts, rf);
  k4ab_slide<<<NREG, 256, 0, stream>>>(rf, Ws, bs, Wsa1, bsa1, Wsa2, bsa2, se, ssb);
  k4c_final<<<1, 256, 0, stream>>>(se, ssb, Wc1, bc1, Wc2, bc2, out);
}

// Round 4
// 662.444 us; speedup vs baseline: 1.2302x; 1.2302x over previous
//
#include <hip/hip_runtime.h>

// ---------------- constants ----------------
#define NTOK 65536
#define DIN  1024
#define H    512
#define HH   256
#define NREG 16
#define MPR  4096   // patches per region = NTOK/NREG

// ---------------- helpers ----------------
__device__ __forceinline__ unsigned short f2bf(float f) {
  unsigned u = __float_as_uint(f);
  u += 0x7fffu + ((u >> 16) & 1u);   // RNE
  return (unsigned short)(u >> 16);
}
__device__ __forceinline__ float bf2f(unsigned short s) {
  return __uint_as_float(((unsigned)s) << 16);
}
// A&S 7.1.26 erf, |err| < 1.5e-7 (far below Eb's bf16 quantum)
__device__ __forceinline__ float gelu_fast(float x) {
  float ax = fabsf(x) * 0.70710678118654752f;   // |x|/sqrt(2)
  float t  = 1.0f / fmaf(0.3275911f, ax, 1.0f);
  float poly = t * fmaf(t, fmaf(t, fmaf(t, fmaf(t, 1.061405429f, -1.453152027f),
                                        1.421413741f), -0.284496736f), 0.254829592f);
  float erfv = fmaf(-poly, __expf(-ax * ax), 1.0f);
  float s = (x >= 0.0f) ? erfv : -erfv;
  return 0.5f * x * (1.0f + s);
}
__device__ __forceinline__ float tanh_fast(float x) {
  float e = __expf(2.0f * x);        // x<<0 -> 0 -> -1 ; x>>0 -> inf -> +1
  return 1.0f - 2.0f / (e + 1.0f);
}

typedef __attribute__((ext_vector_type(8))) short shortx8;  // 8 bf16 (4 VGPRs)
typedef __attribute__((ext_vector_type(4))) float floatx4;  // 4 fp32

__device__ __forceinline__ void gl_lds16(const void* g, void* l) {
  __builtin_amdgcn_global_load_lds(
      (const __attribute__((address_space(1))) void*)g,
      (__attribute__((address_space(3))) void*)l, 16, 0, 0);
}

// ---------------- KP: fused prep — X fp32->bf16 stream + weight transposes --
// blocks [0, 32768): convert X (8 elems/thread). blocks [32768, 35328): weights.
__global__ __launch_bounds__(256) void kp_prep(const float* __restrict__ X,
                                               const float* __restrict__ W1,
                                               const float* __restrict__ Wa1,
                                               unsigned short* __restrict__ Xb,
                                               unsigned short* __restrict__ W1t,
                                               unsigned short* __restrict__ Wa1t) {
  if (blockIdx.x < 32768) {
    size_t i = ((size_t)blockIdx.x * 256 + threadIdx.x) * 8;
    const floatx4* src = (const floatx4*)(X + i);
    floatx4 f0 = src[0], f1 = src[1];
    shortx8 h;
    h[0] = (short)f2bf(f0[0]); h[1] = (short)f2bf(f0[1]);
    h[2] = (short)f2bf(f0[2]); h[3] = (short)f2bf(f0[3]);
    h[4] = (short)f2bf(f1[0]); h[5] = (short)f2bf(f1[1]);
    h[6] = (short)f2bf(f1[2]); h[7] = (short)f2bf(f1[3]);
    *(shortx8*)(Xb + i) = h;
  } else {
    int idx = (blockIdx.x - 32768) * 256 + threadIdx.x;
    if (idx < DIN * H) {                 // 524288
      int n = idx >> 10, k = idx & 1023; // W1t[n][k] = W1[k][n]
      W1t[idx] = f2bf(W1[k * H + n]);
    } else {
      int i2 = idx - DIN * H;            // < 131072
      int n = i2 >> 9, k = i2 & 511;     // Wa1t[n][k] = Wa1[k][n]
      Wa1t[i2] = f2bf(Wa1[k * HH + n]);
    }
  }
}

// LDS tiles: 128 rows x 64 shorts (8 x 16B chunks/row, 128 B = full bank wrap).
// XOR swizzle: physical chunk = logical chunk ^ (row & 7) -> 2-way aliasing on
// fragment reads (free; R3 measured SQ_LDS_BANK_CONFLICT = 0). Staging
// inverse-permutes the GLOBAL chunk index (stays within the row's 128 B ->
// coalescing preserved).

// ---------------- K1: Eb = GELU(Xb @ W1t^T + b1), bf16 in/out ----------------
// M=65536, K=1024, N=512. BM=BN=128, BK=64. grid(4, 512) = 2048 blocks, 256 thr.
__global__ __launch_bounds__(256) void k1_gemm1(const unsigned short* __restrict__ Xb,
                                                const unsigned short* __restrict__ W1t,
                                                const float* __restrict__ b1,
                                                unsigned short* __restrict__ Eb) {
  __shared__ __align__(16) short lA[128 * 64];   // 16 KB
  __shared__ __align__(16) short lB[128 * 64];   // 16 KB
  const int tid = threadIdx.x;
  const int colBase = blockIdx.x * 128;
  const int rowBase = blockIdx.y * 128;
  const int lane = tid & 63;
  const int wave = tid >> 6;
  const int wr = wave >> 1, wc = wave & 1;  // 2x2 waves of 64x64
  const int l15 = lane & 15, quad = lane >> 4;
  const int rsw = l15 & 7;                  // fragment-read swizzle term

  floatx4 acc[4][4] = {};

  for (int kb = 0; kb < DIN; kb += 64) {
    __syncthreads();
#pragma unroll
    for (int s = 0; s < 4; s++) {
      int c = tid + s * 256;
      int row = c >> 3;
      int kc_ = (c & 7) ^ (row & 7);        // inverse of XOR swizzle
      gl_lds16(Xb + (size_t)(rowBase + row) * DIN + kb + kc_ * 8, &lA[c * 8]);
      gl_lds16(W1t + (size_t)(colBase + row) * DIN + kb + kc_ * 8, &lB[c * 8]);
    }
    __syncthreads();
#pragma unroll
    for (int h = 0; h < 2; h++) {
      shortx8 aF[4], bF[4];
#pragma unroll
      for (int i = 0; i < 4; i++)
        aF[i] = *(const shortx8*)(&lA[(wr * 64 + i * 16 + l15) * 64 + (((h << 2) + quad) ^ rsw) * 8]);
#pragma unroll
      for (int j = 0; j < 4; j++)
        bF[j] = *(const shortx8*)(&lB[(wc * 64 + j * 16 + l15) * 64 + (((h << 2) + quad) ^ rsw) * 8]);
#pragma unroll
      for (int i = 0; i < 4; i++)
#pragma unroll
        for (int j = 0; j < 4; j++)
          acc[i][j] = __builtin_amdgcn_mfma_f32_16x16x32_bf16(aF[i], bF[j], acc[i][j], 0, 0, 0);
    }
  }

  // epilogue: bias + fast-exact GELU + bf16 store
  const int row0 = rowBase + wr * 64;
  const int col0 = colBase + wc * 64;
#pragma unroll
  for (int j = 0; j < 4; j++) {
    int col = col0 + j * 16 + l15;
    float bias = b1[col];
#pragma unroll
    for (int i = 0; i < 4; i++) {
      int rb = row0 + i * 16 + quad * 4;
#pragma unroll
      for (int v = 0; v < 4; v++)
        Eb[(size_t)(rb + v) * H + col] = f2bf(gelu_fast(acc[i][j][v] + bias));
    }
  }
}

// ---------------- K2: scores += tanh(Eb @ Wa1 + ba1) . Wa2  (fused) ----------------
// M=65536, K=512, N=256. BM=BN=128, BK=64. grid(2, 512) = 1024 blocks.
// scores pre-zeroed.
__global__ __launch_bounds__(256) void k2_gemm2(const unsigned short* __restrict__ Eb,
                                                const unsigned short* __restrict__ Wa1t,
                                                const float* __restrict__ ba1,
                                                const float* __restrict__ Wa2,
                                                float* __restrict__ scores) {
  __shared__ __align__(16) short lA[128 * 64];
  __shared__ __align__(16) short lB[128 * 64];
  const int tid = threadIdx.x;
  const int colBase = blockIdx.x * 128;
  const int rowBase = blockIdx.y * 128;
  const int lane = tid & 63;
  const int wave = tid >> 6;
  const int wr = wave >> 1, wc = wave & 1;
  const int l15 = lane & 15, quad = lane >> 4;
  const int rsw = l15 & 7;

  floatx4 acc[4][4] = {};

  for (int kb = 0; kb < H; kb += 64) {
    __syncthreads();
#pragma unroll
    for (int s = 0; s < 4; s++) {
      int c = tid + s * 256;
      int row = c >> 3;
      int kc_ = (c & 7) ^ (row & 7);
      gl_lds16(Eb + (size_t)(rowBase + row) * H + kb + kc_ * 8, &lA[c * 8]);
      gl_lds16(Wa1t + (size_t)(colBase + row) * H + kb + kc_ * 8, &lB[c * 8]);
    }
    __syncthreads();
#pragma unroll
    for (int h = 0; h < 2; h++) {
      shortx8 aF[4], bF[4];
#pragma unroll
      for (int i = 0; i < 4; i++)
        aF[i] = *(const shortx8*)(&lA[(wr * 64 + i * 16 + l15) * 64 + (((h << 2) + quad) ^ rsw) * 8]);
#pragma unroll
      for (int j = 0; j < 4; j++)
        bF[j] = *(const shortx8*)(&lB[(wc * 64 + j * 16 + l15) * 64 + (((h << 2) + quad) ^ rsw) * 8]);
#pragma unroll
      for (int i = 0; i < 4; i++)
#pragma unroll
        for (int j = 0; j < 4; j++)
          acc[i][j] = __builtin_amdgcn_mfma_f32_16x16x32_bf16(aF[i], bF[j], acc[i][j], 0, 0, 0);
    }
  }

  // epilogue: p = sum_cols tanh(acc + ba1[col]) * Wa2[col]; reduce over 16 lanes
  float p[4][4];
#pragma unroll
  for (int i = 0; i < 4; i++)
#pragma unroll
    for (int v = 0; v < 4; v++) p[i][v] = 0.0f;
#pragma unroll
  for (int j = 0; j < 4; j++) {
    int col = colBase + wc * 64 + j * 16 + l15;
    float bias = ba1[col];
    float wa2 = Wa2[col];
#pragma unroll
    for (int i = 0; i < 4; i++)
#pragma unroll
      for (int v = 0; v < 4; v++)
        p[i][v] += tanh_fast(acc[i][j][v] + bias) * wa2;
  }
#pragma unroll
  for (int i = 0; i < 4; i++)
#pragma unroll
    for (int v = 0; v < 4; v++) {
      float t = p[i][v];
      t += __shfl_xor(t, 1, 16);
      t += __shfl_xor(t, 2, 16);
      t += __shfl_xor(t, 4, 16);
      t += __shfl_xor(t, 8, 16);
      p[i][v] = t;
    }
  if (l15 == 0) {
    int row0 = rowBase + wr * 64 + quad * 4;
#pragma unroll
    for (int i = 0; i < 4; i++)
#pragma unroll
      for (int v = 0; v < 4; v++)
        atomicAdd(&scores[row0 + i * 16 + v], p[i][v]);
  }
}

// ---------------- K3a: per-region softmax weights ----------------
__global__ __launch_bounds__(256) void k3a_softmax(const float* __restrict__ scores,
                                                   float* __restrict__ wts) {
  const int r = blockIdx.x, tid = threadIdx.x;
  __shared__ float red[256];
  float m = -1e30f;
  for (int j = tid; j < MPR; j += 256) m = fmaxf(m, scores[r + NREG * j]);
  red[tid] = m;
  __syncthreads();
  for (int s = 128; s > 0; s >>= 1) {
    if (tid < s) red[tid] = fmaxf(red[tid], red[tid + s]);
    __syncthreads();
  }
  float mx = red[0];
  __syncthreads();
  float sum = 0.0f;
  for (int j = tid; j < MPR; j += 256) sum += expf(scores[r + NREG * j] - mx);
  red[tid] = sum;
  __syncthreads();
  for (int s = 128; s > 0; s >>= 1) {
    if (tid < s) red[tid] += red[tid + s];
    __syncthreads();
  }
  float inv = 1.0f / red[0];
  for (int j = tid; j < MPR; j += 256)
    wts[r + NREG * j] = expf(scores[r + NREG * j] - mx) * inv;
}

// ---------------- K3b: region_features[r][h] = sum_m w * Eb ----------------
__global__ __launch_bounds__(256) void k3b_wsum(const unsigned short* __restrict__ Eb,
                                                const float* __restrict__ wts,
                                                float* __restrict__ rf) {
  const int r = blockIdx.y;
  const int mc = blockIdx.x;
  const int tid = threadIdx.x;
  float a0 = 0.0f, a1 = 0.0f;
  for (int j = mc * 128; j < mc * 128 + 128; j++) {
    int n = r + NREG * j;
    float w = wts[n];
    unsigned v = *(const unsigned*)(Eb + (size_t)n * H + tid * 2);
    a0 += w * bf2f((unsigned short)(v & 0xffffu));
    a1 += w * bf2f((unsigned short)(v >> 16));
  }
  atomicAdd(&rf[r * H + tid * 2], a0);
  atomicAdd(&rf[r * H + tid * 2 + 1], a1);
}

// ---------------- K4ab: slide_emb + slide attention score (fused) ----------------
__global__ __launch_bounds__(256) void k4ab_slide(const float* __restrict__ rf,
                                                  const float* __restrict__ Ws,
                                                  const float* __restrict__ bs,
                                                  const float* __restrict__ Wsa1,
                                                  const float* __restrict__ bsa1,
                                                  const float* __restrict__ Wsa2,
                                                  const float* __restrict__ bsa2,
                                                  float* __restrict__ se,
                                                  float* __restrict__ ss) {
  const int r = blockIdx.x, tid = threadIdx.x;
  __shared__ float lrf[H];
  __shared__ float lse[H];
  __shared__ float red[256];
  lrf[tid] = rf[r * H + tid];
  lrf[tid + 256] = rf[r * H + tid + 256];
  __syncthreads();
  float a0 = 0.0f, a1 = 0.0f;
  for (int k = 0; k < H; k++) {
    float x = lrf[k];
    a0 += x * Ws[k * H + tid];
    a1 += x * Ws[k * H + tid + 256];
  }
  float s0 = gelu_fast(a0 + bs[tid]);
  float s1 = gelu_fast(a1 + bs[tid + 256]);
  se[r * H + tid] = s0;
  se[r * H + tid + 256] = s1;
  lse[tid] = s0;
  lse[tid + 256] = s1;
  __syncthreads();
  float a = 0.0f;
  for (int k = 0; k < H; k++) a += lse[k] * Wsa1[k * HH + tid];
  red[tid] = tanh_fast(a + bsa1[tid]) * Wsa2[tid];
  __syncthreads();
  for (int s = 128; s > 0; s >>= 1) {
    if (tid < s) red[tid] += red[tid + s];
    __syncthreads();
  }
  if (tid == 0) ss[r] = red[0] + bsa2[0];
}

// ---------------- K4c: softmax over regions + classifier ----------------
__global__ __launch_bounds__(256) void k4c_final(const float* __restrict__ se,
                                                 const float* __restrict__ ss,
                                                 const float* __restrict__ Wc1,
                                                 const float* __restrict__ bc1,
                                                 const float* __restrict__ Wc2,
                                                 const float* __restrict__ bc2,
                                                 float* __restrict__ out) {
  const int tid = threadIdx.x;
  __shared__ float srep[H];
  __shared__ float r0[256], r1[256];
  float mx = -1e30f;
  for (int i = 0; i < NREG; i++) mx = fmaxf(mx, ss[i]);
  float wv[NREG];
  float den = 0.0f;
  for (int i = 0; i < NREG; i++) { wv[i] = expf(ss[i] - mx); den += wv[i]; }
  float inv = 1.0f / den;
  float s0 = 0.0f, s1 = 0.0f;
  for (int i = 0; i < NREG; i++) {
    float w = wv[i] * inv;
    s0 += w * se[i * H + tid];
    s1 += w * se[i * H + tid + 256];
  }
  srep[tid] = s0;
  srep[tid + 256] = s1;
  __syncthreads();
  float a = 0.0f;
  for (int k = 0; k < H; k++) a += srep[k] * Wc1[k * HH + tid];
  float g = gelu_fast(a + bc1[tid]);
  r0[tid] = g * Wc2[tid * 2];
  r1[tid] = g * Wc2[tid * 2 + 1];
  __syncthreads();
  for (int s = 128; s > 0; s >>= 1) {
    if (tid < s) { r0[tid] += r0[tid + s]; r1[tid] += r1[tid + s]; }
    __syncthreads();
  }
  if (tid == 0) {
    out[0] = r0[0] + bc2[0];
    out[1] = r1[0] + bc2[1];
  }
}

// ---------------- launcher ----------------
extern "C" void kernel_launch(void* const* d_in, const int* in_sizes, int n_in,
                              void* d_out, int out_size, void* d_ws, size_t ws_size,
                              hipStream_t stream) {
  const float* X    = (const float*)d_in[0];
  const float* W1   = (const float*)d_in[1];
  const float* b1   = (const float*)d_in[2];
  const float* Wa1  = (const float*)d_in[3];
  const float* ba1  = (const float*)d_in[4];
  const float* Wa2  = (const float*)d_in[5];
  // d_in[6] = ba2: constant shift inside softmax -> no effect, unused
  const float* Ws   = (const float*)d_in[7];
  const float* bs   = (const float*)d_in[8];
  const float* Wsa1 = (const float*)d_in[9];
  const float* bsa1 = (const float*)d_in[10];
  const float* Wsa2 = (const float*)d_in[11];
  const float* bsa2 = (const float*)d_in[12];
  const float* Wc1  = (const float*)d_in[13];
  const float* bc1  = (const float*)d_in[14];
  const float* Wc2  = (const float*)d_in[15];
  const float* bc2  = (const float*)d_in[16];
  float* out = (float*)d_out;

  char* ws = (char*)d_ws;
  constexpr size_t OFF_W1T  = 0;                                    // 1 MiB
  constexpr size_t OFF_WA1T = OFF_W1T + (size_t)H * DIN * 2;        // +256 KiB
  constexpr size_t OFF_EB   = OFF_WA1T + (size_t)HH * H * 2;        // +64 MiB
  constexpr size_t OFF_SC   = OFF_EB + (size_t)NTOK * H * 2;        // scores 256 KiB
  constexpr size_t OFF_RF   = OFF_SC + (size_t)NTOK * 4;            // rf 32 KiB
  constexpr size_t OFF_WT   = OFF_RF + (size_t)NREG * H * 4;        // wts 256 KiB
  constexpr size_t OFF_SE   = OFF_WT + (size_t)NTOK * 4;            // se 32 KiB
  constexpr size_t OFF_SS   = OFF_SE + (size_t)NREG * H * 4;        // ss 64 B
  constexpr size_t OFF_XB   = OFF_SS + 256;                         // Xb 128 MiB

  unsigned short* W1t  = (unsigned short*)(ws + OFF_W1T);
  unsigned short* Wa1t = (unsigned short*)(ws + OFF_WA1T);
  unsigned short* Eb   = (unsigned short*)(ws + OFF_EB);
  float* scores = (float*)(ws + OFF_SC);
  float* rf     = (float*)(ws + OFF_RF);
  float* wts    = (float*)(ws + OFF_WT);
  float* se     = (float*)(ws + OFF_SE);
  float* ssb    = (float*)(ws + OFF_SS);
  unsigned short* Xb = (unsigned short*)(ws + OFF_XB);

  // zero the atomic accumulators (scores + rf are contiguous)
  hipMemsetAsync(scores, 0, (size_t)NTOK * 4 + (size_t)NREG * H * 4, stream);

  kp_prep<<<32768 + 2560, 256, 0, stream>>>(X, W1, Wa1, Xb, W1t, Wa1t);
  k1_gemm1<<<dim3(4, 512), 256, 0, stream>>>(Xb, W1t, b1, Eb);
  k2_gemm2<<<dim3(2, 512), 256, 0, stream>>>(Eb, Wa1t, ba1, Wa2, scores);
  k3a_softmax<<<NREG, 256, 0, stream>>>(scores, wts);
  k3b_wsum<<<dim3(32, NREG), 256, 0, stream>>>(Eb, wts, rf);
  k4ab_slide<<<NREG, 256, 0, stream>>>(rf, Ws, bs, Wsa1, bsa1, Wsa2, bsa2, se, ssb);
  k4c_final<<<1, 256, 0, stream>>>(se, ssb, Wc1, bc1, Wc2, bc2, out);
}